// Round 8
// baseline (154.741 us; speedup 1.0000x reference)
//
#include <hip/hip_runtime.h>

#define N_ATOMS 65536
#define N_MOL 512

typedef __attribute__((ext_vector_type(8))) __bf16 bf16x8;
typedef __attribute__((ext_vector_type(4))) float f32x4;

__device__ __forceinline__ unsigned int f2bf(float f) {
    unsigned int u = __float_as_uint(f);
    return (u + 0x7fffu + ((u >> 16) & 1u)) >> 16;
}

__device__ __forceinline__ int pack2(float a, float b) {
    return (int)(f2bf(a) | (f2bf(b) << 16));
}

__device__ __forceinline__ float silu(float v) {
    return v / (1.0f + __expf(-v));
}

// async global->LDS, 16B per lane, linear dest (wave-uniform base + lane*16)
#define GLDS16(gp, lp)                                                        \
    __builtin_amdgcn_global_load_lds(                                         \
        (__attribute__((address_space(1))) void*)(uintptr_t)(gp),             \
        (__attribute__((address_space(3))) void*)(uintptr_t)(lp), 16, 0, 0)

// ws layout (shorts): W1ps'[4*512*256] | W2ps[4*256*256] | W1mp'[4*256*256] | W2mp[4*256*256]
// (W1' = gamma-folded). Then floats at byte 2621440: gW1ps[1024] bW1ps[1024] gW1mp[1024] bW1mp[1024]
#define WS_W1PS 0
#define WS_W2PS 524288
#define WS_W1MP 786432
#define WS_W2MP 1048576
#define WS_GB_BYTES 2621440

// Weight prep, LDS-free (proven). Per-32k chunk sub-image: [256 n][32 k] bf16 = 1024 int4;
// global short offset = ch*8192 + i16*8 + (klc&7), i16 = n*4 + ((klc>>3) ^ ((n>>1)&3)).
__global__ __launch_bounds__(256) void prep_w(const float* __restrict__ Wps1,
                                              const float* __restrict__ Wps2,
                                              const float* __restrict__ Wmp1,
                                              const float* __restrict__ Wmp2,
                                              const float* __restrict__ g_ps,
                                              const float* __restrict__ b_ps,
                                              const float* __restrict__ g_mp,
                                              const float* __restrict__ b_mp,
                                              short* __restrict__ wdst,
                                              float* __restrict__ gb) {
    int b = blockIdx.x;
    const float* src; int K; long dstbase; int s, c;
    const float* ga = nullptr; const float* be = nullptr; float* gbd = nullptr;
    if (b < 32)      { src = Wps1; K = 512; s = b >> 3;        c = b & 7;        dstbase = WS_W1PS;
                       ga = g_ps; be = b_ps; gbd = gb; }
    else if (b < 48) { src = Wps2; K = 256; s = (b - 32) >> 2; c = (b - 32) & 3; dstbase = WS_W2PS; }
    else if (b < 64) { src = Wmp1; K = 256; s = (b - 48) >> 2; c = (b - 48) & 3; dstbase = WS_W1MP;
                       ga = g_mp; be = b_mp; gbd = gb + 2048; }
    else             { src = Wmp2; K = 256; s = (b - 64) >> 2; c = (b - 64) & 3; dstbase = WS_W2MP; }
    int n = threadIdx.x;   // output column 0..255
    int k0 = c * 64;
    const float* sp = src + (long)s * K * 256 + (long)k0 * 256 + n;
    int4* dstc = (int4*)(wdst + dstbase + (long)s * K * 256 + (long)c * 16384);
    float gs = 0.0f, bs = 0.0f;
    #pragma unroll 2
    for (int j = 0; j < 8; ++j) {          // j: group of 8 consecutive k
        unsigned int hh[8];
        #pragma unroll
        for (int i = 0; i < 8; ++i) {
            int kl = j * 8 + i;
            float v = sp[(long)kl * 256];
            float w = ga ? v * ga[k0 + kl] : v;
            hh[i] = f2bf(w);
            if (ga) {
                gs += __uint_as_float(hh[i] << 16);
                bs += be[k0 + kl] * v;
            }
        }
        int4 p;
        p.x = (int)(hh[0] | (hh[1] << 16));
        p.y = (int)(hh[2] | (hh[3] << 16));
        p.z = (int)(hh[4] | (hh[5] << 16));
        p.w = (int)(hh[6] | (hh[7] << 16));
        int ch = j >> 2;                    // which 32-k sub-image
        int i16 = n * 4 + ((j & 3) ^ ((n >> 1) & 3));
        dstc[ch * 1024 + i16] = p;
    }
    if (ga) {
        atomicAdd(&gbd[s * 256 + n], gs);
        atomicAdd(&gbd[1024 + s * 256 + n], bs);
    }
}

// LDS arena (bytes):
//   GEMM1 live: P0 0..32768 (BK=64 B tile = two 16K sub-images) | As 32768..40960 (two 4K subs)
//   GEMM2 live: B 0..16384 (reuses P0 lower half) | H1 16384..49152 (P0 upper + As, dead)
//   stats 49152..49664 | elds 49664..49920
#define OFF_P0    0
#define OFF_AS    32768
#define OFF_H1    16384
#define OFF_STATS 49152
#define OFF_ELDS  49664
#define ARENA_BYTES 49920

#define STAGE_B(gbase, lbase)                                                 \
    do {                                                                      \
        const int4* _g = (const int4*)(gbase);                                \
        int4* _l = (int4*)(lbase);                                            \
        _Pragma("unroll")                                                     \
        for (int _q = 0; _q < 4; ++_q) {                                      \
            int _idx = wid * 256 + _q * 64;                                   \
            GLDS16(_g + _idx + lane, _l + _idx);                              \
        }                                                                     \
    } while (0)

template <int NPH>   // NPH = F/64 phases (8 for ps, 4 for mp)
__device__ __forceinline__ void mlp_body(
    char* arena,
    const float* __restrict__ x, const short* __restrict__ W1,
    const short* __restrict__ W2, const float* __restrict__ gW1,
    const float* __restrict__ bW1, const float* __restrict__ W3,
    const int* __restrict__ batch, float* __restrict__ out, int tile) {
    short* P0  = (short*)(arena + OFF_P0);
    short* As  = (short*)(arena + OFF_AS);
    short* H1  = (short*)(arena + OFF_H1);
    float2* rowstats = (float2*)(arena + OFF_STATS);
    float*  e_lds    = (float*)(arena + OFF_ELDS);

    const int tid = threadIdx.x;
    const int lane = tid & 63;
    const int wid = tid >> 6;
    const int wn = wid * 64;
    const int lg = lane >> 4;
    const int ln = lane & 15;
    const int swz = lg ^ ((ln >> 1) & 3);          // fragment-read 16B-block swizzle

    constexpr int F = NPH * 64;
    const int block0 = tile * 64;
    const int species = block0 >> 14;
    const short* W1s = W1 + (size_t)species * NPH * 16384;
    const short* W2s = W2 + (size_t)species * 65536;

    if (tid < 64) e_lds[tid] = 0.0f;
    const int mol = (tid < 64) ? batch[block0 + tid] : 0;

    float gwv[4], bwv[4], w3v[4];
    #pragma unroll
    for (int n = 0; n < 4; ++n) {
        int col = wn + n * 16 + ln;
        gwv[n] = gW1[species * 256 + col];
        bwv[n] = bW1[species * 256 + col];
        w3v[n] = W3[species * 256 + col];
    }

    const int ar = tid >> 2;
    const int aj = tid & 3;
    const float* xrow = x + (size_t)(block0 + ar) * F + aj * 8;
    const int i16a = ar * 4 + (aj ^ ((ar >> 1) & 3));   // A-stage write 16B-slot

    f32x4 acc[4][4];
    #pragma unroll
    for (int m = 0; m < 4; ++m)
        #pragma unroll
        for (int n = 0; n < 4; ++n) acc[m][n] = (f32x4){0.f, 0.f, 0.f, 0.f};
    float s1 = 0.0f, s2 = 0.0f;

    // ---- GEMM1: BK=64 phases, proven 2-barrier schedule per phase ----
    #pragma unroll 1
    for (int p = 0; p < NPH; ++p) {
        if (p) __syncthreads();             // previous compute's P0/As reads drained
        // x loads for both 32-k sub-chunks (issue before GLDS)
        float4 u0 = *(const float4*)(xrow + p * 64);
        float4 v0 = *(const float4*)(xrow + p * 64 + 4);
        float4 u1 = *(const float4*)(xrow + p * 64 + 32);
        float4 v1 = *(const float4*)(xrow + p * 64 + 36);
        // stage 32KB of B (two consecutive sub-images)
        STAGE_B(W1s + (size_t)p * 16384, P0);
        STAGE_B(W1s + (size_t)p * 16384 + 8192, P0 + 8192);
        // stats + pack both sub-chunks
        s1 += u0.x + u0.y + u0.z + u0.w + v0.x + v0.y + v0.z + v0.w
            + u1.x + u1.y + u1.z + u1.w + v1.x + v1.y + v1.z + v1.w;
        s2 += u0.x * u0.x + u0.y * u0.y + u0.z * u0.z + u0.w * u0.w
            + v0.x * v0.x + v0.y * v0.y + v0.z * v0.z + v0.w * v0.w
            + u1.x * u1.x + u1.y * u1.y + u1.z * u1.z + u1.w * u1.w
            + v1.x * v1.x + v1.y * v1.y + v1.z * v1.z + v1.w * v1.w;
        {
            int4 q;
            q.x = pack2(u0.x, u0.y); q.y = pack2(u0.z, u0.w);
            q.z = pack2(v0.x, v0.y); q.w = pack2(v0.z, v0.w);
            *(int4*)&As[i16a * 8] = q;
            q.x = pack2(u1.x, u1.y); q.y = pack2(u1.z, u1.w);
            q.z = pack2(v1.x, v1.y); q.w = pack2(v1.z, v1.w);
            *(int4*)&As[2048 + i16a * 8] = q;
        }
        __syncthreads();                    // GLDS + x + A-pack drained
        #pragma unroll
        for (int ks = 0; ks < 2; ++ks) {
            bf16x8 a[4], b[4];
            #pragma unroll
            for (int m = 0; m < 4; ++m)
                a[m] = *(const bf16x8*)&As[ks * 2048 + (m * 64 + ln * 4 + swz) * 8];
            #pragma unroll
            for (int n = 0; n < 4; ++n)
                b[n] = *(const bf16x8*)&P0[ks * 8192 + (wn * 4 + n * 64 + ln * 4 + swz) * 8];
            #pragma unroll
            for (int m = 0; m < 4; ++m)
                #pragma unroll
                for (int n = 0; n < 4; ++n)
                    acc[m][n] = __builtin_amdgcn_mfma_f32_16x16x32_bf16(a[m], b[n], acc[m][n], 0, 0, 0);
        }
    }

    // ---- LN stats finalize ----
    s1 += __shfl_xor(s1, 1); s1 += __shfl_xor(s1, 2);
    s2 += __shfl_xor(s2, 1); s2 += __shfl_xor(s2, 2);
    if (aj == 0) rowstats[ar] = make_float2(s1, s2);
    __syncthreads();            // rowstats visible; all P0/As reads drained

    // stage W2(0) -> lower 16K (latency covered by fixup VALU below)
    STAGE_B(W2s, P0);

    // ---- LN fixup + SiLU -> H1 (overwrites P0 upper half + As; both dead) ----
    const float invF = 1.0f / (float)F;
    #pragma unroll
    for (int m = 0; m < 4; ++m) {
        #pragma unroll
        for (int rr = 0; rr < 4; ++rr) {
            int row = m * 16 + lg * 4 + rr;
            float2 rs = rowstats[row];
            float mu = rs.x * invF;
            float var = rs.y * invF - mu * mu;
            float rstd = rsqrtf(var + 1e-5f);
            float nmu = rstd * mu;
            #pragma unroll
            for (int n = 0; n < 4; ++n) {
                float vv = rstd * acc[m][n][rr] - nmu * gwv[n] + bwv[n];
                int col = wn + n * 16 + ln;
                H1[(row * 256 + col) ^ ((row & 7) << 3)] = (short)f2bf(silu(vv));
            }
        }
    }
    __syncthreads();            // H1 visible + W2(0) GLDS drained

    // ---- GEMM2: H1 @ W2 (proven structure) ----
    f32x4 acc2[4][4];
    #pragma unroll
    for (int m = 0; m < 4; ++m)
        #pragma unroll
        for (int n = 0; n < 4; ++n) acc2[m][n] = (f32x4){0.f, 0.f, 0.f, 0.f};

    #pragma unroll 1
    for (int c = 0; c < 8; ++c) {
        bf16x8 a[4], b[4];
        #pragma unroll
        for (int m = 0; m < 4; ++m)
            a[m] = *(const bf16x8*)&H1[m * 4096 + ln * 256 + ((c * 32 + lg * 8) ^ ((ln & 7) << 3))];
        #pragma unroll
        for (int n = 0; n < 4; ++n)
            b[n] = *(const bf16x8*)&P0[(wn * 4 + n * 64 + ln * 4 + swz) * 8];
        __syncthreads();        // all waves' B reads complete
        if (c < 7)
            STAGE_B(W2s + (size_t)(c + 1) * 8192, P0);
        #pragma unroll
        for (int m = 0; m < 4; ++m)
            #pragma unroll
            for (int n = 0; n < 4; ++n)
                acc2[m][n] = __builtin_amdgcn_mfma_f32_16x16x32_bf16(a[m], b[n], acc2[m][n], 0, 0, 0);
        __syncthreads();        // GLDS(c+1) landed (covered by the 16 MFMAs above)
    }

    // ---- SiLU + dot W3 + scatter ----
    #pragma unroll
    for (int m = 0; m < 4; ++m) {
        #pragma unroll
        for (int rr = 0; rr < 4; ++rr) {
            int row = m * 16 + lg * 4 + rr;
            float p = 0.0f;
            #pragma unroll
            for (int n = 0; n < 4; ++n) p += silu(acc2[m][n][rr]) * w3v[n];
            p += __shfl_xor(p, 1); p += __shfl_xor(p, 2);
            p += __shfl_xor(p, 4); p += __shfl_xor(p, 8);
            if (ln == 0) atomicAdd(&e_lds[row], p);
        }
    }
    __syncthreads();
    if (tid < 64) atomicAdd(out + mol, e_lds[tid]);
}

__global__ __launch_bounds__(256, 3) void mlp_all(
    const float* __restrict__ x_ps, const float* __restrict__ x_mp,
    const short* __restrict__ wimg, const float* __restrict__ gb,
    const float* __restrict__ W3ps, const float* __restrict__ W3mp,
    const int* __restrict__ batch, float* __restrict__ out) {
    __shared__ __align__(16) char arena[ARENA_BYTES];
    if (blockIdx.x < 1024) {
        mlp_body<8>(arena, x_ps, wimg + WS_W1PS, wimg + WS_W2PS,
                    gb + 0, gb + 1024, W3ps, batch, out, (int)blockIdx.x);
    } else {
        mlp_body<4>(arena, x_mp, wimg + WS_W1MP, wimg + WS_W2MP,
                    gb + 2048, gb + 3072, W3mp, batch, out, (int)blockIdx.x - 1024);
    }
}

extern "C" void kernel_launch(void* const* d_in, const int* in_sizes, int n_in,
                              void* d_out, int out_size, void* d_ws, size_t ws_size,
                              hipStream_t stream) {
    const float* x_ps     = (const float*)d_in[0];
    const float* x_mp     = (const float*)d_in[1];
    const int*   batch    = (const int*)d_in[2];
    const float* gamma_ps = (const float*)d_in[3];
    const float* beta_ps  = (const float*)d_in[4];
    const float* gamma_mp = (const float*)d_in[5];
    const float* beta_mp  = (const float*)d_in[6];
    const float* W_ps1    = (const float*)d_in[7];
    const float* W_ps2    = (const float*)d_in[8];
    const float* W_ps3    = (const float*)d_in[9];
    const float* W_mp1    = (const float*)d_in[10];
    const float* W_mp2    = (const float*)d_in[11];
    const float* W_mp3    = (const float*)d_in[12];

    float* out = (float*)d_out;
    short* wsW = (short*)d_ws;
    float* gb  = (float*)((char*)d_ws + WS_GB_BYTES);

    hipMemsetAsync(out, 0, N_MOL * sizeof(float), stream);
    hipMemsetAsync(gb, 0, 4096 * sizeof(float), stream);

    hipLaunchKernelGGL(prep_w, dim3(80), dim3(256), 0, stream,
                       W_ps1, W_ps2, W_mp1, W_mp2,
                       gamma_ps, beta_ps, gamma_mp, beta_mp, wsW, gb);

    hipLaunchKernelGGL(mlp_all, dim3(2048), dim3(256), 0, stream,
                       x_ps, x_mp, wsW, gb, W_ps3, W_mp3, batch, out);
}

// Round 9
// 151.039 us; speedup vs baseline: 1.0245x; 1.0245x over previous
//
#include <hip/hip_runtime.h>
#include <hip/hip_bf16.h>

#define N_ATOMS 65536
#define N_MOL 512

typedef __attribute__((ext_vector_type(8))) __bf16 bf16x8;
typedef __attribute__((ext_vector_type(4))) float f32x4;

__device__ __forceinline__ unsigned int f2bf(float f) {
    unsigned int u = __float_as_uint(f);
    return (u + 0x7fffu + ((u >> 16) & 1u)) >> 16;
}

// native packed convert: compiler emits v_cvt_pk_bf16_f32 (RNE, same bits as f2bf)
__device__ __forceinline__ int pack2n(float a, float b) {
    union { __hip_bfloat162 h; int u; } c;
    c.h = __float22bfloat162_rn(make_float2(a, b));
    return c.u;
}

__device__ __forceinline__ short bf1(float a) {
    union { __hip_bfloat16 h; short s; } c;
    c.h = __float2bfloat16(a);
    return c.s;
}

__device__ __forceinline__ float silu(float v) {
    return v / (1.0f + __expf(-v));
}

// async global->LDS, 16B per lane, linear dest (wave-uniform base + lane*16)
#define GLDS16(gp, lp)                                                        \
    __builtin_amdgcn_global_load_lds(                                         \
        (__attribute__((address_space(1))) void*)(uintptr_t)(gp),             \
        (__attribute__((address_space(3))) void*)(uintptr_t)(lp), 16, 0, 0)

// ws layout (shorts): W1ps'[4*512*256] | W2ps[4*256*256] | W1mp'[4*256*256] | W2mp[4*256*256]
// (W1' = gamma-folded). Then floats at byte 2621440: gW1ps[1024] bW1ps[1024] gW1mp[1024] bW1mp[1024]
#define WS_W1PS 0
#define WS_W2PS 524288
#define WS_W1MP 786432
#define WS_W2MP 1048576
#define WS_GB_BYTES 2621440

// Weight prep, LDS-free (proven). Per-32k chunk sub-image: [256 n][32 k] bf16 = 1024 int4;
// global short offset = ch*8192 + i16*8 + (klc&7), i16 = n*4 + ((klc>>3) ^ ((n>>1)&3)).
__global__ __launch_bounds__(256) void prep_w(const float* __restrict__ Wps1,
                                              const float* __restrict__ Wps2,
                                              const float* __restrict__ Wmp1,
                                              const float* __restrict__ Wmp2,
                                              const float* __restrict__ g_ps,
                                              const float* __restrict__ b_ps,
                                              const float* __restrict__ g_mp,
                                              const float* __restrict__ b_mp,
                                              short* __restrict__ wdst,
                                              float* __restrict__ gb) {
    int b = blockIdx.x;
    const float* src; int K; long dstbase; int s, c;
    const float* ga = nullptr; const float* be = nullptr; float* gbd = nullptr;
    if (b < 32)      { src = Wps1; K = 512; s = b >> 3;        c = b & 7;        dstbase = WS_W1PS;
                       ga = g_ps; be = b_ps; gbd = gb; }
    else if (b < 48) { src = Wps2; K = 256; s = (b - 32) >> 2; c = (b - 32) & 3; dstbase = WS_W2PS; }
    else if (b < 64) { src = Wmp1; K = 256; s = (b - 48) >> 2; c = (b - 48) & 3; dstbase = WS_W1MP;
                       ga = g_mp; be = b_mp; gbd = gb + 2048; }
    else             { src = Wmp2; K = 256; s = (b - 64) >> 2; c = (b - 64) & 3; dstbase = WS_W2MP; }
    int n = threadIdx.x;   // output column 0..255
    int k0 = c * 64;
    const float* sp = src + (long)s * K * 256 + (long)k0 * 256 + n;
    int4* dstc = (int4*)(wdst + dstbase + (long)s * K * 256 + (long)c * 16384);
    float gs = 0.0f, bs = 0.0f;
    #pragma unroll 2
    for (int j = 0; j < 8; ++j) {          // j: group of 8 consecutive k
        unsigned int hh[8];
        #pragma unroll
        for (int i = 0; i < 8; ++i) {
            int kl = j * 8 + i;
            float v = sp[(long)kl * 256];
            float w = ga ? v * ga[k0 + kl] : v;
            hh[i] = f2bf(w);
            if (ga) {
                gs += __uint_as_float(hh[i] << 16);
                bs += be[k0 + kl] * v;
            }
        }
        int4 p;
        p.x = (int)(hh[0] | (hh[1] << 16));
        p.y = (int)(hh[2] | (hh[3] << 16));
        p.z = (int)(hh[4] | (hh[5] << 16));
        p.w = (int)(hh[6] | (hh[7] << 16));
        int ch = j >> 2;                    // which 32-k sub-image
        int i16 = n * 4 + ((j & 3) ^ ((n >> 1) & 3));
        dstc[ch * 1024 + i16] = p;
    }
    if (ga) {
        atomicAdd(&gbd[s * 256 + n], gs);
        atomicAdd(&gbd[1024 + s * 256 + n], bs);
    }
}

// LDS arena (bytes):
//   GEMM1 live: P0 0..32768 (BK=64 B tile = two 16K sub-images) | As 32768..40960 (two 4K subs)
//   GEMM2 live: B 0..16384 (reuses P0 lower half) | H1 16384..49152 (P0 upper + As, dead)
//   stats 49152..49664 | elds 49664..49920
#define OFF_P0    0
#define OFF_AS    32768
#define OFF_H1    16384
#define OFF_STATS 49152
#define OFF_ELDS  49664
#define ARENA_BYTES 49920

#define STAGE_B(gbase, lbase)                                                 \
    do {                                                                      \
        const int4* _g = (const int4*)(gbase);                                \
        int4* _l = (int4*)(lbase);                                            \
        _Pragma("unroll")                                                     \
        for (int _q = 0; _q < 4; ++_q) {                                      \
            int _idx = wid * 256 + _q * 64;                                   \
            GLDS16(_g + _idx + lane, _l + _idx);                              \
        }                                                                     \
    } while (0)

template <int NPH>   // NPH = F/64 phases (8 for ps, 4 for mp)
__device__ __forceinline__ void mlp_body(
    char* arena,
    const float* __restrict__ x, const short* __restrict__ W1,
    const short* __restrict__ W2, const float* __restrict__ gW1,
    const float* __restrict__ bW1, const float* __restrict__ W3,
    const int* __restrict__ batch, float* __restrict__ out, int tile) {
    short* P0  = (short*)(arena + OFF_P0);
    short* As  = (short*)(arena + OFF_AS);
    short* H1  = (short*)(arena + OFF_H1);
    float2* rowstats = (float2*)(arena + OFF_STATS);
    float*  e_lds    = (float*)(arena + OFF_ELDS);

    const int tid = threadIdx.x;
    const int lane = tid & 63;
    const int wid = tid >> 6;
    const int wn = wid * 64;
    const int lg = lane >> 4;
    const int ln = lane & 15;
    const int swz = lg ^ ((ln >> 1) & 3);          // fragment-read 16B-block swizzle

    constexpr int F = NPH * 64;
    const int block0 = tile * 64;
    const int species = block0 >> 14;
    const short* W1s = W1 + (size_t)species * NPH * 16384;
    const short* W2s = W2 + (size_t)species * 65536;

    if (tid < 64) e_lds[tid] = 0.0f;
    const int mol = (tid < 64) ? batch[block0 + tid] : 0;

    float gwv[4], bwv[4], w3v[4];
    #pragma unroll
    for (int n = 0; n < 4; ++n) {
        int col = wn + n * 16 + ln;
        gwv[n] = gW1[species * 256 + col];
        bwv[n] = bW1[species * 256 + col];
        w3v[n] = W3[species * 256 + col];
    }

    const int ar = tid >> 2;
    const int aj = tid & 3;
    const float* xrow = x + (size_t)(block0 + ar) * F + aj * 8;
    const int i16a = ar * 4 + (aj ^ ((ar >> 1) & 3));   // A-stage write 16B-slot

    f32x4 acc[4][4];
    #pragma unroll
    for (int m = 0; m < 4; ++m)
        #pragma unroll
        for (int n = 0; n < 4; ++n) acc[m][n] = (f32x4){0.f, 0.f, 0.f, 0.f};
    float s1 = 0.0f, s2 = 0.0f;

    // current-phase x registers (depth-1 prefetch)
    float4 cu0 = *(const float4*)(xrow);
    float4 cv0 = *(const float4*)(xrow + 4);
    float4 cu1 = *(const float4*)(xrow + 32);
    float4 cv1 = *(const float4*)(xrow + 36);

    // ---- GEMM1: BK=64 phases, proven 2-barrier schedule per phase ----
    #pragma unroll 1
    for (int p = 0; p < NPH; ++p) {
        if (p) __syncthreads();             // previous compute's P0/As reads drained
        // prefetch next phase's x (registers only; no LDS hazard)
        float4 nu0, nv0, nu1, nv1;
        if (p + 1 < NPH) {
            nu0 = *(const float4*)(xrow + (p + 1) * 64);
            nv0 = *(const float4*)(xrow + (p + 1) * 64 + 4);
            nu1 = *(const float4*)(xrow + (p + 1) * 64 + 32);
            nv1 = *(const float4*)(xrow + (p + 1) * 64 + 36);
        }
        // stage 32KB of B (two consecutive sub-images)
        STAGE_B(W1s + (size_t)p * 16384, P0);
        STAGE_B(W1s + (size_t)p * 16384 + 8192, P0 + 8192);
        // stats + pack both sub-chunks (current regs)
        s1 += cu0.x + cu0.y + cu0.z + cu0.w + cv0.x + cv0.y + cv0.z + cv0.w
            + cu1.x + cu1.y + cu1.z + cu1.w + cv1.x + cv1.y + cv1.z + cv1.w;
        s2 += cu0.x * cu0.x + cu0.y * cu0.y + cu0.z * cu0.z + cu0.w * cu0.w
            + cv0.x * cv0.x + cv0.y * cv0.y + cv0.z * cv0.z + cv0.w * cv0.w
            + cu1.x * cu1.x + cu1.y * cu1.y + cu1.z * cu1.z + cu1.w * cu1.w
            + cv1.x * cv1.x + cv1.y * cv1.y + cv1.z * cv1.z + cv1.w * cv1.w;
        {
            int4 q;
            q.x = pack2n(cu0.x, cu0.y); q.y = pack2n(cu0.z, cu0.w);
            q.z = pack2n(cv0.x, cv0.y); q.w = pack2n(cv0.z, cv0.w);
            *(int4*)&As[i16a * 8] = q;
            q.x = pack2n(cu1.x, cu1.y); q.y = pack2n(cu1.z, cu1.w);
            q.z = pack2n(cv1.x, cv1.y); q.w = pack2n(cv1.z, cv1.w);
            *(int4*)&As[2048 + i16a * 8] = q;
        }
        __syncthreads();                    // GLDS + A-pack drained
        #pragma unroll
        for (int ks = 0; ks < 2; ++ks) {
            bf16x8 a[4], b[4];
            #pragma unroll
            for (int m = 0; m < 4; ++m)
                a[m] = *(const bf16x8*)&As[ks * 2048 + (m * 64 + ln * 4 + swz) * 8];
            #pragma unroll
            for (int n = 0; n < 4; ++n)
                b[n] = *(const bf16x8*)&P0[ks * 8192 + (wn * 4 + n * 64 + ln * 4 + swz) * 8];
            __builtin_amdgcn_s_setprio(1);
            #pragma unroll
            for (int m = 0; m < 4; ++m)
                #pragma unroll
                for (int n = 0; n < 4; ++n)
                    acc[m][n] = __builtin_amdgcn_mfma_f32_16x16x32_bf16(a[m], b[n], acc[m][n], 0, 0, 0);
            __builtin_amdgcn_s_setprio(0);
        }
        if (p + 1 < NPH) { cu0 = nu0; cv0 = nv0; cu1 = nu1; cv1 = nv1; }
    }

    // ---- LN stats finalize ----
    s1 += __shfl_xor(s1, 1); s1 += __shfl_xor(s1, 2);
    s2 += __shfl_xor(s2, 1); s2 += __shfl_xor(s2, 2);
    if (aj == 0) rowstats[ar] = make_float2(s1, s2);
    __syncthreads();            // rowstats visible; all P0/As reads drained

    // stage W2(0) -> lower 16K (latency covered by fixup VALU below)
    STAGE_B(W2s, P0);

    // ---- LN fixup + SiLU -> H1 (overwrites P0 upper half + As; both dead) ----
    const float invF = 1.0f / (float)F;
    #pragma unroll
    for (int m = 0; m < 4; ++m) {
        #pragma unroll
        for (int rr = 0; rr < 4; ++rr) {
            int row = m * 16 + lg * 4 + rr;
            float2 rs = rowstats[row];
            float mu = rs.x * invF;
            float var = rs.y * invF - mu * mu;
            float rstd = rsqrtf(var + 1e-5f);
            float nmu = rstd * mu;
            #pragma unroll
            for (int n = 0; n < 4; ++n) {
                float vv = rstd * acc[m][n][rr] - nmu * gwv[n] + bwv[n];
                int col = wn + n * 16 + ln;
                H1[(row * 256 + col) ^ ((row & 7) << 3)] = bf1(silu(vv));
            }
        }
    }
    __syncthreads();            // H1 visible + W2(0) GLDS drained

    // ---- GEMM2: H1 @ W2 (proven structure) ----
    f32x4 acc2[4][4];
    #pragma unroll
    for (int m = 0; m < 4; ++m)
        #pragma unroll
        for (int n = 0; n < 4; ++n) acc2[m][n] = (f32x4){0.f, 0.f, 0.f, 0.f};

    #pragma unroll 1
    for (int c = 0; c < 8; ++c) {
        bf16x8 a[4], b[4];
        #pragma unroll
        for (int m = 0; m < 4; ++m)
            a[m] = *(const bf16x8*)&H1[m * 4096 + ln * 256 + ((c * 32 + lg * 8) ^ ((ln & 7) << 3))];
        #pragma unroll
        for (int n = 0; n < 4; ++n)
            b[n] = *(const bf16x8*)&P0[(wn * 4 + n * 64 + ln * 4 + swz) * 8];
        __syncthreads();        // all waves' B reads complete
        if (c < 7)
            STAGE_B(W2s + (size_t)(c + 1) * 8192, P0);
        __builtin_amdgcn_s_setprio(1);
        #pragma unroll
        for (int m = 0; m < 4; ++m)
            #pragma unroll
            for (int n = 0; n < 4; ++n)
                acc2[m][n] = __builtin_amdgcn_mfma_f32_16x16x32_bf16(a[m], b[n], acc2[m][n], 0, 0, 0);
        __builtin_amdgcn_s_setprio(0);
        __syncthreads();        // GLDS(c+1) landed (covered by the 16 MFMAs above)
    }

    // ---- SiLU + dot W3 + scatter ----
    #pragma unroll
    for (int m = 0; m < 4; ++m) {
        #pragma unroll
        for (int rr = 0; rr < 4; ++rr) {
            int row = m * 16 + lg * 4 + rr;
            float p = 0.0f;
            #pragma unroll
            for (int n = 0; n < 4; ++n) p += silu(acc2[m][n][rr]) * w3v[n];
            p += __shfl_xor(p, 1); p += __shfl_xor(p, 2);
            p += __shfl_xor(p, 4); p += __shfl_xor(p, 8);
            if (ln == 0) atomicAdd(&e_lds[row], p);
        }
    }
    __syncthreads();
    if (tid < 64) atomicAdd(out + mol, e_lds[tid]);
}

__global__ __launch_bounds__(256, 3) void mlp_all(
    const float* __restrict__ x_ps, const float* __restrict__ x_mp,
    const short* __restrict__ wimg, const float* __restrict__ gb,
    const float* __restrict__ W3ps, const float* __restrict__ W3mp,
    const int* __restrict__ batch, float* __restrict__ out) {
    __shared__ __align__(16) char arena[ARENA_BYTES];
    if (blockIdx.x < 1024) {
        mlp_body<8>(arena, x_ps, wimg + WS_W1PS, wimg + WS_W2PS,
                    gb + 0, gb + 1024, W3ps, batch, out, (int)blockIdx.x);
    } else {
        mlp_body<4>(arena, x_mp, wimg + WS_W1MP, wimg + WS_W2MP,
                    gb + 2048, gb + 3072, W3mp, batch, out, (int)blockIdx.x - 1024);
    }
}

extern "C" void kernel_launch(void* const* d_in, const int* in_sizes, int n_in,
                              void* d_out, int out_size, void* d_ws, size_t ws_size,
                              hipStream_t stream) {
    const float* x_ps     = (const float*)d_in[0];
    const float* x_mp     = (const float*)d_in[1];
    const int*   batch    = (const int*)d_in[2];
    const float* gamma_ps = (const float*)d_in[3];
    const float* beta_ps  = (const float*)d_in[4];
    const float* gamma_mp = (const float*)d_in[5];
    const float* beta_mp  = (const float*)d_in[6];
    const float* W_ps1    = (const float*)d_in[7];
    const float* W_ps2    = (const float*)d_in[8];
    const float* W_ps3    = (const float*)d_in[9];
    const float* W_mp1    = (const float*)d_in[10];
    const float* W_mp2    = (const float*)d_in[11];
    const float* W_mp3    = (const float*)d_in[12];

    float* out = (float*)d_out;
    short* wsW = (short*)d_ws;
    float* gb  = (float*)((char*)d_ws + WS_GB_BYTES);

    hipMemsetAsync(out, 0, N_MOL * sizeof(float), stream);
    hipMemsetAsync(gb, 0, 4096 * sizeof(float), stream);

    hipLaunchKernelGGL(prep_w, dim3(80), dim3(256), 0, stream,
                       W_ps1, W_ps2, W_mp1, W_mp2,
                       gamma_ps, beta_ps, gamma_mp, beta_mp, wsW, gb);

    hipLaunchKernelGGL(mlp_all, dim3(2048), dim3(256), 0, stream,
                       x_ps, x_mp, wsW, gb, W_ps3, W_mp3, batch, out);
}